// Round 4
// baseline (180.970 us; speedup 1.0000x reference)
//
#include <hip/hip_runtime.h>

// DetectionLoss: B=32768, G=7, A=2, C=3, M=20.
// R4: single-pass branchless streaming.
//  - Phase 1: per-target assignment (tv, cw, lab, cell) into LDS; coalesced loads.
//  - Phase 1b: parallel winner test (valid && no LATER same-batch same-cell target
//    == numpy last-write-wins); winner writes s_table[cell]=j directly (unique
//    winner per cell -> race-free, no atomics, no compaction).
//  - Phase 2: ONE pass over preds, 2x float4 per cell (full cacheline use),
//    7 fully-unrolled iters (448 thr x 32 batches = 3136 cells exactly).
//    Per-cell branchless: m in {0,1}; negatives broadcast-read zero slot kTgt.
//    sp(-x) = sp(x) - x avoids a second softplus.
//  - Block partials plain-stored SoA (no global atomics, per R2), tiny reducer.
// R3 post-mortem: divergence removal was neutral (both-paths == branchless);
// the real cost was the two-pass strided-load + scattered-gather structure,
// removed here.

namespace {
constexpr int kG = 7;
constexpr int kA = 2;
constexpr int kM = 20;
constexpr int kCells = kG * kG * kA;       // 98
constexpr int kCh = 8;                     // 5 + C
constexpr int kNB = 32;                    // batches per block
constexpr int kBlock = 448;                // 7 waves; kNB*kCells == 7*kBlock
constexpr int kTgt = kNB * kM;             // 640
constexpr int kCellsBlk = kNB * kCells;    // 3136
constexpr int kIters = kCellsBlk / kBlock; // 7
}

__device__ __forceinline__ float softplus_fast(float x) {
    // logaddexp(x,0); fast exp/log — absmax threshold ~0.56 leaves huge slack
    return fmaxf(x, 0.0f) + __logf(1.0f + __expf(-fabsf(x)));
}

__global__ __launch_bounds__(kBlock) void det_loss_main(
    const float* __restrict__ preds,
    const float* __restrict__ tboxes,
    const int* __restrict__ tlabels,
    const int* __restrict__ nobjs,
    const float* __restrict__ anchors,
    const float* __restrict__ cweights,
    float* __restrict__ partial,   // SoA [5][gridDim.x]: obj, noobj, bbox, cls, npos
    int B)
{
    __shared__ float4 s_tv[kTgt + 1];     // per-target (tx,ty,tw,th); slot kTgt = zeros
    __shared__ float  s_cw[kTgt + 1];     // per-target class weight
    __shared__ int    s_lab[kTgt + 1];    // per-target label
    __shared__ short  s_cell[kTgt];       // block-local cell = bl*98+c, -1 invalid
    __shared__ short  s_table[kCellsBlk]; // cell -> winning target idx, -1 none
    __shared__ int    s_nobj[kNB];
    __shared__ float  s_red[kBlock / 64][4];

    const int tid = threadIdx.x;
    const int b0 = blockIdx.x * kNB;

    if (tid < kNB) {
        const int b = b0 + tid;
        s_nobj[tid] = (b < B) ? nobjs[b] : 0;
    }
    if (tid == 0) {
        s_tv[kTgt] = make_float4(0.f, 0.f, 0.f, 0.f);
        s_cw[kTgt] = 0.f;
        s_lab[kTgt] = 0;
    }
    #pragma unroll
    for (int k = 0; k < kIters; ++k) s_table[tid + k * kBlock] = -1;
    __syncthreads();

    const float a00 = anchors[0], a01 = anchors[1];
    const float a10 = anchors[2], a11 = anchors[3];

    // ---- Phase 1: per-target assignment ----
    for (int j = tid; j < kTgt; j += kBlock) {
        const int bl = j / kM;
        const int m  = j - bl * kM;
        short cell = -1;
        float4 tv = make_float4(0.f, 0.f, 0.f, 0.f);
        float cwv = 0.f;
        int lab = 0;
        if (b0 + bl < B) {
            const float4 box = ((const float4*)tboxes)[(size_t)b0 * kM + j];
            const float x1 = box.x, y1 = box.y, x2 = box.z, y2 = box.w;
            const float cx = (x1 + x2) * 0.5f, cy = (y1 + y2) * 0.5f;
            const float w = x2 - x1, h = y2 - y1;
            if (w > 0.f && h > 0.f && m < s_nobj[bl]) {
                const int gi = min(max((int)floorf(cy * (float)kG), 0), kG - 1);
                const int gj = min(max((int)floorf(cx * (float)kG), 0), kG - 1);
                const float wg = w * (float)kG, hg = h * (float)kG;
                const float i0 = fminf(wg, a00) * fminf(hg, a01);
                const float u0 = wg * hg + a00 * a01 - i0;
                const float r0 = i0 / (u0 + 1e-6f);
                const float i1 = fminf(wg, a10) * fminf(hg, a11);
                const float u1 = wg * hg + a10 * a11 - i1;
                const float r1 = i1 / (u1 + 1e-6f);
                const int a = (r1 > r0) ? 1 : 0;   // argmax, first-max wins
                const float aw = a ? a10 : a00;
                const float ah = a ? a11 : a01;
                tv.x = cx * (float)kG - (float)gj;
                tv.y = cy * (float)kG - (float)gi;
                tv.z = __logf(fmaxf(wg, 0.01f) / (aw + 1e-6f));
                tv.w = __logf(fmaxf(hg, 0.01f) / (ah + 1e-6f));
                cell = (short)(bl * kCells + (gi * kG + gj) * kA + a);
                lab = tlabels[(size_t)b0 * kM + j];
                cwv = cweights[lab];
            }
        }
        s_cell[j] = cell;
        s_tv[j] = tv;
        s_cw[j] = cwv;
        s_lab[j] = lab;
    }
    __syncthreads();

    // ---- Phase 1b: winner test -> direct table write (race-free) ----
    for (int j = tid; j < kTgt; j += kBlock) {
        const short c = s_cell[j];
        if (c >= 0) {
            const int bl = j / kM;
            const int m  = j - bl * kM;
            bool win = true;
            for (int m2 = m + 1; m2 < kM; ++m2) {
                if (s_cell[bl * kM + m2] == c) { win = false; break; }
            }
            if (win) s_table[c] = (short)j;   // unique winner per cell
        }
    }
    __syncthreads();

    // ---- Phase 2: single branchless pass over all cells ----
    float accO = 0.f, accN = 0.f, accB = 0.f, accC = 0.f;
    int npos = 0;
    const float cw0 = cweights[0];  (void)cw0;
    const float4* __restrict__ p4 = (const float4*)preds + (size_t)b0 * kCells * 2;

    if (b0 + kNB <= B) {
        #pragma unroll
        for (int k = 0; k < kIters; ++k) {
            const int i = tid + k * kBlock;
            const float4 p0 = p4[2 * i];
            const float4 p1 = p4[2 * i + 1];
            const int j = s_table[i];          // sign-extended short
            const bool pos = (j >= 0);
            const int jj = pos ? j : kTgt;     // negatives -> zero slot (broadcast)
            const float m = pos ? 1.f : 0.f;
            const float4 tv = s_tv[jj];
            const float cwv = s_cw[jj];
            const int lab = s_lab[jj];

            const float po = p0.x;
            const float spo = softplus_fast(po);
            accN += spo - m * spo;             // (1-m)*sp(po)
            accO += m * (spo - po);            // m*sp(-po)

            float d, ad, sb;
            d = p0.y - tv.x; ad = fabsf(d); sb  = (ad < 1.f) ? 0.5f * d * d : ad - 0.5f;
            d = p0.z - tv.y; ad = fabsf(d); sb += (ad < 1.f) ? 0.5f * d * d : ad - 0.5f;
            d = p0.w - tv.z; ad = fabsf(d); sb += (ad < 1.f) ? 0.5f * d * d : ad - 0.5f;
            d = p1.x - tv.w; ad = fabsf(d); sb += (ad < 1.f) ? 0.5f * d * d : ad - 0.5f;
            accB += m * sb;

            const float c0 = p1.y, c1 = p1.z, c2 = p1.w;
            const float mx = fmaxf(c0, fmaxf(c1, c2));
            const float lse = mx + __logf(__expf(c0 - mx) + __expf(c1 - mx) + __expf(c2 - mx));
            const float logit = (lab == 0) ? c0 : ((lab == 1) ? c1 : c2);
            accC += m * cwv * (lse - logit);
            npos += pos ? 1 : 0;
        }
    } else {
        const int ncell = (B - b0) * kCells;
        for (int i = tid; i < ncell; i += kBlock) {
            const float4 p0 = p4[2 * i];
            const float4 p1 = p4[2 * i + 1];
            const int j = s_table[i];
            const bool pos = (j >= 0);
            const int jj = pos ? j : kTgt;
            const float m = pos ? 1.f : 0.f;
            const float4 tv = s_tv[jj];
            const float cwv = s_cw[jj];
            const int lab = s_lab[jj];
            const float po = p0.x;
            const float spo = softplus_fast(po);
            accN += spo - m * spo;
            accO += m * (spo - po);
            float d, ad, sb;
            d = p0.y - tv.x; ad = fabsf(d); sb  = (ad < 1.f) ? 0.5f * d * d : ad - 0.5f;
            d = p0.z - tv.y; ad = fabsf(d); sb += (ad < 1.f) ? 0.5f * d * d : ad - 0.5f;
            d = p0.w - tv.z; ad = fabsf(d); sb += (ad < 1.f) ? 0.5f * d * d : ad - 0.5f;
            d = p1.x - tv.w; ad = fabsf(d); sb += (ad < 1.f) ? 0.5f * d * d : ad - 0.5f;
            accB += m * sb;
            const float c0 = p1.y, c1 = p1.z, c2 = p1.w;
            const float mx = fmaxf(c0, fmaxf(c1, c2));
            const float lse = mx + __logf(__expf(c0 - mx) + __expf(c1 - mx) + __expf(c2 - mx));
            const float logit = (lab == 0) ? c0 : ((lab == 1) ? c1 : c2);
            accC += m * cwv * (lse - logit);
            npos += pos ? 1 : 0;
        }
    }

    // ---- Block reduce + plain SoA stores ----
    float vals[4] = {accO, accN, accB, accC};
    float npf = (float)npos;
    #pragma unroll
    for (int k = 0; k < 4; ++k) {
        float v = vals[k];
        #pragma unroll
        for (int off = 32; off > 0; off >>= 1) v += __shfl_down(v, off, 64);
        vals[k] = v;
    }
    #pragma unroll
    for (int off = 32; off > 0; off >>= 1) npf += __shfl_down(npf, off, 64);

    __shared__ float s_np[kBlock / 64];
    const int wave = tid >> 6;
    const int lane = tid & 63;
    if (lane == 0) {
        #pragma unroll
        for (int k = 0; k < 4; ++k) s_red[wave][k] = vals[k];
        s_np[wave] = npf;
    }
    __syncthreads();
    if (tid == 0) {
        const int nb = gridDim.x;
        #pragma unroll
        for (int k = 0; k < 4; ++k) {
            float t = 0.f;
            #pragma unroll
            for (int w = 0; w < kBlock / 64; ++w) t += s_red[w][k];
            partial[(size_t)k * nb + blockIdx.x] = t;
        }
        float tn = 0.f;
        #pragma unroll
        for (int w = 0; w < kBlock / 64; ++w) tn += s_np[w];
        partial[(size_t)4 * nb + blockIdx.x] = tn;
    }
}

__global__ __launch_bounds__(256) void det_loss_reduce(
    const float* __restrict__ partial, int nblocks, float* __restrict__ out)
{
    __shared__ float s_red[4][5];
    const int tid = threadIdx.x;
    float v[5] = {0.f, 0.f, 0.f, 0.f, 0.f};
    for (int i = tid; i < nblocks; i += 256) {
        #pragma unroll
        for (int k = 0; k < 5; ++k) v[k] += partial[(size_t)k * nblocks + i];
    }
    #pragma unroll
    for (int k = 0; k < 5; ++k) {
        float x = v[k];
        #pragma unroll
        for (int off = 32; off > 0; off >>= 1) x += __shfl_down(x, off, 64);
        v[k] = x;
    }
    const int wave = tid >> 6;
    const int lane = tid & 63;
    if (lane == 0) {
        #pragma unroll
        for (int k = 0; k < 5; ++k) s_red[wave][k] = v[k];
    }
    __syncthreads();
    if (tid == 0) {
        float t[5];
        #pragma unroll
        for (int k = 0; k < 5; ++k) {
            float s = 0.f;
            #pragma unroll
            for (int w = 0; w < 4; ++w) s += s_red[w][k];
            t[k] = s;
        }
        const float npv = fmaxf(t[4], 1.0f);
        out[0] = (5.0f * t[2] + 1.0f * t[0] + 0.5f * t[1] + 2.0f * t[3]) / npv;
    }
}

extern "C" void kernel_launch(void* const* d_in, const int* in_sizes, int n_in,
                              void* d_out, int out_size, void* d_ws, size_t ws_size,
                              hipStream_t stream) {
    const float* preds    = (const float*)d_in[0];
    const float* tboxes   = (const float*)d_in[1];
    const int*   tlabels  = (const int*)d_in[2];
    const int*   nobjs    = (const int*)d_in[3];
    const float* anchors  = (const float*)d_in[4];
    const float* cweights = (const float*)d_in[5];
    float* out = (float*)d_out;
    float* partial = (float*)d_ws;   // [5][nblocks], fully overwritten every call

    const int B = in_sizes[0] / (kCells * kCh);   // /784
    const int blocks = (B + kNB - 1) / kNB;

    det_loss_main<<<blocks, kBlock, 0, stream>>>(
        preds, tboxes, tlabels, nobjs, anchors, cweights, partial, B);
    det_loss_reduce<<<1, 256, 0, stream>>>(partial, blocks, out);
}